// Round 3
// baseline (3012.886 us; speedup 1.0000x reference)
//
#include <hip/hip_runtime.h>

// LaplaceMeshLoss: COO Laplacian SpMV + per-row norm + weighted scalar reduce.
//
// R3: XCD-partitioned scatter. Rows are split into 8 contiguous ranges, one
// per physical XCD (identified at runtime via s_getreg HW_REG_XCC_ID). Each
// XCD's blocks scan the full COO stream (work-stealing via a per-XCD chunk
// counter) and apply only the entries whose row belongs to their XCD's range,
// using WORKGROUP-scope atomic fadd -> the RMW executes in the local XCD's
// L2 (no sc1 / no memory-side fabric transaction). Atomicity across blocks
// holds because every update to a given row comes from exactly one physical
// XCD's L2. Each XCD's 4 MB row slice fits its 4 MB L2.
//
// ws layout:
//   [0,8)            double partial sum
//   [8,24)           int nvpm[4]
//   [24,56)          int chunk counters[8] (one per XCD)
//   [64, 64+16V)     float4 acc[V]  ({Lx0,Lx1,Lx2,rowsum})
// Zeroed via hipMemsetAsync at launch start.

#define CHUNK_ITER 16
#define SCATTER_THREADS 256
#define CHUNK_SIZE (SCATTER_THREADS * CHUNK_ITER)

__device__ __forceinline__ int get_xcc_id() {
    int x;
    asm volatile("s_getreg_b32 %0, hwreg(HW_REG_XCC_ID)" : "=s"(x));
    return x & 7;
}

__device__ __forceinline__ void wg_atomic_add(float* p, float v) {
    __hip_atomic_fetch_add(p, v, __ATOMIC_RELAXED, __HIP_MEMORY_SCOPE_WORKGROUP);
}

__global__ void scatter_kernel(const float* __restrict__ verts,
                               const float* __restrict__ vals,
                               const int* __restrict__ rows,
                               const int* __restrict__ cols,
                               float* __restrict__ acc,   // [V][4]
                               int* __restrict__ counters,
                               int nnz, int V, int nchunks) {
    const int p = get_xcc_id();
    const int rpp = (V + 7) / 8;
    const int rlo = p * rpp;
    const int rhi = (rlo + rpp < V) ? (rlo + rpp) : V;

    __shared__ int s_chunk;
    for (;;) {
        if (threadIdx.x == 0) s_chunk = atomicAdd(&counters[p], 1);
        __syncthreads();
        int chunk = s_chunk;
        __syncthreads();
        if (chunk >= nchunks) break;

        int base = chunk * CHUNK_SIZE;
        for (int j = 0; j < CHUNK_ITER; ++j) {
            int i = base + j * SCATTER_THREADS + (int)threadIdx.x;
            if (i >= nnz) break;
            int r = rows[i];
            if (r >= rlo && r < rhi) {
                int c = cols[i];
                float v = vals[i];
                float x = verts[3 * c + 0];
                float y = verts[3 * c + 1];
                float z = verts[3 * c + 2];
                float* q = acc + 4ll * r;
                wg_atomic_add(q + 0, v * x);
                wg_atomic_add(q + 1, v * y);
                wg_atomic_add(q + 2, v * z);
                wg_atomic_add(q + 3, v);
            }
        }
    }
}

// verts_mesh_idx is sorted; nvpm[m] = lower_bound(m+1) - lower_bound(m).
__global__ void mesh_counts_kernel(const int* __restrict__ mesh_idx, int v,
                                   int* __restrict__ nvpm) {
    int m = threadIdx.x;
    if (m >= 4) return;
    auto lb = [&](int t) {
        int lo = 0, hi = v;
        while (lo < hi) {
            int mid = (lo + hi) >> 1;
            if (mesh_idx[mid] < t) lo = mid + 1; else hi = mid;
        }
        return lo;
    };
    nvpm[m] = lb(m + 1) - lb(m);
}

__global__ void finalize_kernel(const float* __restrict__ verts,
                                const float* __restrict__ coefs,
                                const int* __restrict__ mesh_idx,
                                const float4* __restrict__ acc,
                                const int* __restrict__ nvpm,
                                double* __restrict__ partial,
                                int v) {
    float inv0 = 1.0f / (float)nvpm[0];
    float inv1 = 1.0f / (float)nvpm[1];
    float inv2 = 1.0f / (float)nvpm[2];
    float inv3 = 1.0f / (float)nvpm[3];

    double acc_sum = 0.0;
    for (int i = blockIdx.x * blockDim.x + threadIdx.x; i < v;
         i += gridDim.x * blockDim.x) {
        float4 a = acc[i];
        float rs = a.w;
        float nw = (rs > 0.0f) ? (1.0f / rs) : rs;
        float r0 = a.x * nw - verts[3 * i + 0];
        float r1 = a.y * nw - verts[3 * i + 1];
        float r2 = a.z * nw - verts[3 * i + 2];
        float loss = sqrtf(r0 * r0 + r1 * r1 + r2 * r2);
        int m = mesh_idx[i];
        float w = (m == 0) ? inv0 : (m == 1) ? inv1 : (m == 2) ? inv2 : inv3;
        acc_sum += (double)(loss * w * coefs[i]);
    }

    __shared__ double sred[256];
    sred[threadIdx.x] = acc_sum;
    __syncthreads();
    for (int s = blockDim.x / 2; s > 0; s >>= 1) {
        if (threadIdx.x < s) sred[threadIdx.x] += sred[threadIdx.x + s];
        __syncthreads();
    }
    if (threadIdx.x == 0) atomicAdd(partial, sred[0]);
}

__global__ void write_out_kernel(const double* __restrict__ partial,
                                 float* __restrict__ out) {
    if (threadIdx.x == 0 && blockIdx.x == 0) {
        out[0] = (float)(partial[0] * 0.25);  // / N_MESHES
    }
}

extern "C" void kernel_launch(void* const* d_in, const int* in_sizes, int n_in,
                              void* d_out, int out_size, void* d_ws, size_t ws_size,
                              hipStream_t stream) {
    const float* verts    = (const float*)d_in[0];
    const float* lap_vals = (const float*)d_in[1];
    const int*   lap_rows = (const int*)d_in[2];
    const int*   lap_cols = (const int*)d_in[3];
    const int*   mesh_idx = (const int*)d_in[4];
    const float* coefs    = (const float*)d_in[5];
    float* out = (float*)d_out;

    const int V   = in_sizes[0] / 3;
    const int NNZ = in_sizes[1];

    char* ws = (char*)d_ws;
    double* partial  = (double*)(ws + 0);
    int*    nvpm     = (int*)(ws + 8);
    int*    counters = (int*)(ws + 24);
    float*  acc      = (float*)(ws + 64);

    size_t zero_bytes = 64 + (size_t)16 * V;
    (void)hipMemsetAsync(d_ws, 0, zero_bytes, stream);

    mesh_counts_kernel<<<1, 64, 0, stream>>>(mesh_idx, V, nvpm);

    {
        int nchunks = (NNZ + CHUNK_SIZE - 1) / CHUNK_SIZE;
        scatter_kernel<<<2048, SCATTER_THREADS, 0, stream>>>(
            verts, lap_vals, lap_rows, lap_cols, acc, counters, NNZ, V, nchunks);
    }

    {
        finalize_kernel<<<2048, 256, 0, stream>>>(
            verts, coefs, mesh_idx, (const float4*)acc, nvpm, partial, V);
    }

    write_out_kernel<<<1, 64, 0, stream>>>(partial, out);
}

// Round 4
// 874.619 us; speedup vs baseline: 3.4448x; 3.4448x over previous
//
#include <hip/hip_runtime.h>

// LaplaceMeshLoss: COO Laplacian SpMV + per-row norm + weighted scalar reduce.
//
// R4: deterministic bucket sort by row (zero global float atomics).
//   Buckets of 1024 rows: bucket = row >> 10, B = ceil(V/1024) <= 2048.
//   P1 hist:    512 blocks LDS-histogram their COO chunk -> hist[b][blk]
//   P2a scan:   per-bucket exclusive scan over the 512 block counts (in place)
//   P2b scan:   exclusive scan of bucket totals -> bucket_base[B+1]
//   P3 scatter: blocks re-read chunk, write (lr<<21|col, val) 8B entries into
//               pre-reserved runs via LDS cursors (LDS atomics only)
//   P4 bucket:  one block per bucket: LDS accumulate {Lx,rowsum} via ds_add,
//               then fused finalize (loss, weights) + double block reduction.
// Global f32 atomic count: ZERO (R1/R3 showed a ~20.6 G atomics/s wall,
// WRITE_SIZE = 56M x 32B regardless of atomic scope).
//
// Sort-path ws layout (needs ~117 MB; falls back to R1 path otherwise):
//   [0,8)        double partial
//   [8,24)       int nvpm[4]
//   [64,...)     uint bucket_base[BMAX+1]
//   [16384,...)  uint total[BMAX]
//   [32768,...)  uint hist[BMAX*NB]            (4 MB)
//   [32768+4MB)  uint2 entries[NNZ]            (112 MB)

#define NB 512            // blocks in hist/scatter phases
#define BMAX 2048         // max buckets
#define BROWS 1024        // rows per bucket

__global__ void mesh_counts_kernel(const int* __restrict__ mesh_idx, int v,
                                   int* __restrict__ nvpm) {
    int m = threadIdx.x;
    if (m >= 4) return;
    auto lb = [&](int t) {
        int lo = 0, hi = v;
        while (lo < hi) {
            int mid = (lo + hi) >> 1;
            if (mesh_idx[mid] < t) lo = mid + 1; else hi = mid;
        }
        return lo;
    };
    nvpm[m] = lb(m + 1) - lb(m);
}

__global__ void hist_kernel(const int* __restrict__ rows, int nnz, int cpb,
                            int B, unsigned* __restrict__ hist) {
    __shared__ unsigned h[BMAX];
    for (int b = threadIdx.x; b < B; b += blockDim.x) h[b] = 0;
    __syncthreads();
    int k = blockIdx.x;
    int i0 = k * cpb;
    int i1 = min(i0 + cpb, nnz);
    for (int i = i0 + (int)threadIdx.x; i < i1; i += blockDim.x)
        atomicAdd(&h[rows[i] >> 10], 1u);
    __syncthreads();
    for (int b = threadIdx.x; b < B; b += blockDim.x)
        hist[(unsigned)b * NB + k] = h[b];
}

// One block per bucket: exclusive scan of hist[b][0..NB) in place, total out.
__global__ void scan_blocks_kernel(unsigned* __restrict__ hist,
                                   unsigned* __restrict__ total) {
    __shared__ unsigned buf0[NB], buf1[NB];
    int b = blockIdx.x;
    int t = threadIdx.x;          // NB threads
    unsigned orig = hist[(unsigned)b * NB + t];
    buf0[t] = orig;
    __syncthreads();
    unsigned* src = buf0;
    unsigned* dst = buf1;
    unsigned v = orig;
    for (int off = 1; off < NB; off <<= 1) {
        v = src[t];
        if (t >= off) v += src[t - off];
        dst[t] = v;
        __syncthreads();
        unsigned* tmp = src; src = dst; dst = tmp;
    }
    hist[(unsigned)b * NB + t] = v - orig;   // exclusive
    if (t == NB - 1) total[b] = v;
}

// Single block: exclusive scan of total[0..B) -> base[0..2048].
__global__ void scan_buckets_kernel(const unsigned* __restrict__ total,
                                    unsigned* __restrict__ base, int B) {
    __shared__ unsigned buf0[1024], buf1[1024];
    int t = threadIdx.x;          // 1024 threads, 2 elems each
    unsigned x0 = (2 * t < B) ? total[2 * t] : 0u;
    unsigned x1 = (2 * t + 1 < B) ? total[2 * t + 1] : 0u;
    unsigned pair = x0 + x1;
    buf0[t] = pair;
    __syncthreads();
    unsigned* src = buf0;
    unsigned* dst = buf1;
    unsigned v = pair;
    for (int off = 1; off < 1024; off <<= 1) {
        v = src[t];
        if (t >= off) v += src[t - off];
        dst[t] = v;
        __syncthreads();
        unsigned* tmp = src; src = dst; dst = tmp;
    }
    unsigned excl = v - pair;
    base[2 * t] = excl;
    base[2 * t + 1] = excl + x0;
    if (t == 1023) base[2048] = v;
}

__global__ void scatter_kernel(const int* __restrict__ rows,
                               const int* __restrict__ cols,
                               const float* __restrict__ vals,
                               const unsigned* __restrict__ hist,
                               const unsigned* __restrict__ base,
                               uint2* __restrict__ dst,
                               int nnz, int cpb, int B) {
    __shared__ unsigned cur[BMAX];
    int k = blockIdx.x;
    for (int b = threadIdx.x; b < B; b += blockDim.x)
        cur[b] = base[b] + hist[(unsigned)b * NB + k];
    __syncthreads();
    int i0 = k * cpb;
    int i1 = min(i0 + cpb, nnz);
    for (int i = i0 + (int)threadIdx.x; i < i1; i += blockDim.x) {
        int r = rows[i];
        unsigned c = (unsigned)cols[i];
        float v = vals[i];
        int b = r >> 10;
        unsigned pos = atomicAdd(&cur[b], 1u);   // LDS atomic
        uint2 e;
        e.x = ((unsigned)(r & (BROWS - 1)) << 21) | c;
        e.y = __float_as_uint(v);
        dst[pos] = e;
    }
}

// One block per bucket: LDS accumulate + fused finalize.
__global__ void bucket_kernel(const uint2* __restrict__ entries,
                              const unsigned* __restrict__ base,
                              const float* __restrict__ verts,
                              const float* __restrict__ coefs,
                              const int* __restrict__ mesh_idx,
                              const int* __restrict__ nvpm,
                              double* __restrict__ partial, int V) {
    __shared__ float ax[BROWS], ay[BROWS], az[BROWS], aw[BROWS];
    int b = blockIdx.x;
    for (int j = threadIdx.x; j < BROWS; j += blockDim.x) {
        ax[j] = 0.f; ay[j] = 0.f; az[j] = 0.f; aw[j] = 0.f;
    }
    __syncthreads();
    unsigned s0 = base[b], s1 = base[b + 1];
    for (unsigned i = s0 + threadIdx.x; i < s1; i += blockDim.x) {
        uint2 e = entries[i];
        unsigned lr = e.x >> 21;
        unsigned c = e.x & 0x1FFFFFu;
        float v = __uint_as_float(e.y);
        float x = verts[3 * c + 0];
        float y = verts[3 * c + 1];
        float z = verts[3 * c + 2];
        atomicAdd(&ax[lr], v * x);
        atomicAdd(&ay[lr], v * y);
        atomicAdd(&az[lr], v * z);
        atomicAdd(&aw[lr], v);
    }
    __syncthreads();

    float inv0 = 1.0f / (float)nvpm[0];
    float inv1 = 1.0f / (float)nvpm[1];
    float inv2 = 1.0f / (float)nvpm[2];
    float inv3 = 1.0f / (float)nvpm[3];

    double acc = 0.0;
    int r0 = b << 10;
    for (int j = threadIdx.x; j < BROWS; j += blockDim.x) {
        int r = r0 + j;
        if (r < V) {
            float rs = aw[j];
            float nw = (rs > 0.0f) ? (1.0f / rs) : rs;
            float d0 = ax[j] * nw - verts[3 * r + 0];
            float d1 = ay[j] * nw - verts[3 * r + 1];
            float d2 = az[j] * nw - verts[3 * r + 2];
            float loss = sqrtf(d0 * d0 + d1 * d1 + d2 * d2);
            int m = mesh_idx[r];
            float w = (m == 0) ? inv0 : (m == 1) ? inv1 : (m == 2) ? inv2 : inv3;
            acc += (double)(loss * w * coefs[r]);
        }
    }

    __shared__ double sred[256];
    sred[threadIdx.x] = acc;
    __syncthreads();
    for (int s = blockDim.x / 2; s > 0; s >>= 1) {
        if (threadIdx.x < s) sred[threadIdx.x] += sred[threadIdx.x + s];
        __syncthreads();
    }
    if (threadIdx.x == 0) atomicAdd(partial, sred[0]);
}

__global__ void write_out_kernel(const double* __restrict__ partial,
                                 float* __restrict__ out) {
    if (threadIdx.x == 0 && blockIdx.x == 0)
        out[0] = (float)(partial[0] * 0.25);  // / N_MESHES
}

// ---- Fallback path (R1): global-atomic scatter, needs only 64 + 16V ws ----

__global__ void fb_scatter_kernel(const float* __restrict__ verts,
                                  const float* __restrict__ vals,
                                  const int* __restrict__ rows,
                                  const int* __restrict__ cols,
                                  float* __restrict__ acc, int nnz) {
    int i = blockIdx.x * blockDim.x + threadIdx.x;
    if (i >= nnz) return;
    int r = rows[i];
    int c = cols[i];
    float v = vals[i];
    float* p = acc + 4ll * r;
    atomicAdd(p + 0, v * verts[3 * c + 0]);
    atomicAdd(p + 1, v * verts[3 * c + 1]);
    atomicAdd(p + 2, v * verts[3 * c + 2]);
    atomicAdd(p + 3, v);
}

__global__ void fb_finalize_kernel(const float* __restrict__ verts,
                                   const float* __restrict__ coefs,
                                   const int* __restrict__ mesh_idx,
                                   const float4* __restrict__ acc,
                                   const int* __restrict__ nvpm,
                                   double* __restrict__ partial, int v) {
    float inv0 = 1.0f / (float)nvpm[0];
    float inv1 = 1.0f / (float)nvpm[1];
    float inv2 = 1.0f / (float)nvpm[2];
    float inv3 = 1.0f / (float)nvpm[3];
    double acc_sum = 0.0;
    for (int i = blockIdx.x * blockDim.x + threadIdx.x; i < v;
         i += gridDim.x * blockDim.x) {
        float4 a = acc[i];
        float rs = a.w;
        float nw = (rs > 0.0f) ? (1.0f / rs) : rs;
        float r0 = a.x * nw - verts[3 * i + 0];
        float r1 = a.y * nw - verts[3 * i + 1];
        float r2 = a.z * nw - verts[3 * i + 2];
        float loss = sqrtf(r0 * r0 + r1 * r1 + r2 * r2);
        int m = mesh_idx[i];
        float w = (m == 0) ? inv0 : (m == 1) ? inv1 : (m == 2) ? inv2 : inv3;
        acc_sum += (double)(loss * w * coefs[i]);
    }
    __shared__ double sred[256];
    sred[threadIdx.x] = acc_sum;
    __syncthreads();
    for (int s = blockDim.x / 2; s > 0; s >>= 1) {
        if (threadIdx.x < s) sred[threadIdx.x] += sred[threadIdx.x + s];
        __syncthreads();
    }
    if (threadIdx.x == 0) atomicAdd(partial, sred[0]);
}

extern "C" void kernel_launch(void* const* d_in, const int* in_sizes, int n_in,
                              void* d_out, int out_size, void* d_ws, size_t ws_size,
                              hipStream_t stream) {
    const float* verts    = (const float*)d_in[0];
    const float* lap_vals = (const float*)d_in[1];
    const int*   lap_rows = (const int*)d_in[2];
    const int*   lap_cols = (const int*)d_in[3];
    const int*   mesh_idx = (const int*)d_in[4];
    const float* coefs    = (const float*)d_in[5];
    float* out = (float*)d_out;

    const int V   = in_sizes[0] / 3;
    const int NNZ = in_sizes[1];
    const int B   = (V + BROWS - 1) / BROWS;   // <= BMAX for V <= 2M
    const int cpb = (NNZ + NB - 1) / NB;

    char* ws = (char*)d_ws;
    double*   partial = (double*)(ws + 0);
    int*      nvpm    = (int*)(ws + 8);
    unsigned* base    = (unsigned*)(ws + 64);
    unsigned* total   = (unsigned*)(ws + 16384);
    unsigned* hist    = (unsigned*)(ws + 32768);
    uint2*    entries = (uint2*)(ws + 32768 + (size_t)BMAX * NB * 4);

    size_t sort_need = 32768 + (size_t)BMAX * NB * 4 + (size_t)NNZ * 8 + 64;

    (void)hipMemsetAsync(d_ws, 0, 64, stream);
    mesh_counts_kernel<<<1, 64, 0, stream>>>(mesh_idx, V, nvpm);

    if (ws_size >= sort_need && B <= BMAX) {
        hist_kernel<<<NB, 256, 0, stream>>>(lap_rows, NNZ, cpb, B, hist);
        scan_blocks_kernel<<<B, NB, 0, stream>>>(hist, total);
        scan_buckets_kernel<<<1, 1024, 0, stream>>>(total, base, B);
        scatter_kernel<<<NB, 256, 0, stream>>>(lap_rows, lap_cols, lap_vals,
                                               hist, base, entries, NNZ, cpb, B);
        bucket_kernel<<<B, 256, 0, stream>>>(entries, base, verts, coefs,
                                             mesh_idx, nvpm, partial, V);
    } else {
        float* acc = (float*)(ws + 64);
        (void)hipMemsetAsync(ws + 64, 0, (size_t)16 * V, stream);
        fb_scatter_kernel<<<(NNZ + 255) / 256, 256, 0, stream>>>(
            verts, lap_vals, lap_rows, lap_cols, acc, NNZ);
        fb_finalize_kernel<<<2048, 256, 0, stream>>>(
            verts, coefs, mesh_idx, (const float4*)acc, nvpm, partial, V);
    }

    write_out_kernel<<<1, 64, 0, stream>>>(partial, out);
}

// Round 5
// 847.817 us; speedup vs baseline: 3.5537x; 1.0316x over previous
//
#include <hip/hip_runtime.h>

// LaplaceMeshLoss: COO Laplacian SpMV + per-row norm + weighted scalar reduce.
//
// R5: same deterministic bucket-sort pipeline as R4 (zero global f32 atomics),
// tuned for latency/occupancy:
//   - NB 512 -> 1024 blocks for hist/scatter (occupancy 23% -> ~46%); hist
//     stored as ushort so the hist array stays 4 MB (ws need unchanged).
//   - scatter: 2-wide ILP (int2/float2 loads, two independent LDS-atomic ->
//     store chains per iteration).
//   - bucket: 512 threads/block + uint4 loads (2 entries/thread/iter) to hide
//     the random verts-gather latency.
//   - scans: wave-shfl scan (2 barriers); mesh_counts folded into bucket scan.
//
// ws layout (sort path, ~117 MB; falls back to R1 path otherwise):
//   [0,8)        double partial
//   [8,24)       int nvpm[4]
//   [64,8260)    uint bucket_base[BMAX+1]
//   [16384,...)  uint total[BMAX]
//   [32768,...)  ushort hist[BMAX*NB]          (4 MB)
//   [32768+4MB)  uint2 entries[NNZ]            (112 MB)

#define NB 1024           // blocks in hist/scatter phases
#define BMAX 2048         // max buckets
#define BROWS 1024        // rows per bucket

__global__ void hist_kernel(const int* __restrict__ rows, int nnz, int cpb,
                            int B, unsigned short* __restrict__ hist) {
    __shared__ unsigned h[BMAX];
    for (int b = threadIdx.x; b < B; b += blockDim.x) h[b] = 0;
    __syncthreads();
    int k = blockIdx.x;
    int i0 = k * cpb;
    int i1 = min(i0 + cpb, nnz);
    for (int i = i0 + 4 * (int)threadIdx.x; i < i1; i += 4 * blockDim.x) {
        if (i + 3 < i1) {
            int4 r4 = *(const int4*)(rows + i);
            atomicAdd(&h[r4.x >> 10], 1u);
            atomicAdd(&h[r4.y >> 10], 1u);
            atomicAdd(&h[r4.z >> 10], 1u);
            atomicAdd(&h[r4.w >> 10], 1u);
        } else {
            for (int j = i; j < i1; ++j) atomicAdd(&h[rows[j] >> 10], 1u);
        }
    }
    __syncthreads();
    for (int b = threadIdx.x; b < B; b += blockDim.x)
        hist[(size_t)b * NB + k] = (unsigned short)h[b];
}

// One block per bucket: exclusive scan of hist[b][0..NB) in place (ushort),
// bucket total out. 256 threads x 4 elems, wave-shfl scan.
__global__ void scan_blocks_kernel(unsigned short* __restrict__ hist,
                                   unsigned* __restrict__ total) {
    int b = blockIdx.x;
    int t = threadIdx.x;            // 256 threads
    int lane = t & 63, wave = t >> 6;
    unsigned short* hp = hist + (size_t)b * NB;
    ushort4 hv = ((const ushort4*)hp)[t];
    unsigned a0 = hv.x, a1 = hv.y, a2 = hv.z, a3 = hv.w;
    unsigned sum = a0 + a1 + a2 + a3;
    unsigned x = sum;
    for (int off = 1; off < 64; off <<= 1) {
        unsigned y = __shfl_up(x, off);
        if (lane >= off) x += y;
    }
    __shared__ unsigned wsum[4];
    if (lane == 63) wsum[wave] = x;
    __syncthreads();
    unsigned woff = 0;
    for (int w = 0; w < wave; ++w) woff += wsum[w];
    unsigned excl = woff + x - sum;
    ushort4 ov;
    ov.x = (unsigned short)excl;
    ov.y = (unsigned short)(excl + a0);
    ov.z = (unsigned short)(excl + a0 + a1);
    ov.w = (unsigned short)(excl + a0 + a1 + a2);
    ((ushort4*)hp)[t] = ov;
    if (t == 255) total[b] = woff + x;
}

// Single block: exclusive scan of total[0..B) -> base[0..2048], plus folded
// mesh_counts (verts_mesh_idx sorted -> 4 binary searches).
__global__ void scan_buckets_kernel(const unsigned* __restrict__ total,
                                    unsigned* __restrict__ base, int B,
                                    const int* __restrict__ mesh_idx, int v,
                                    int* __restrict__ nvpm) {
    int t = threadIdx.x;            // 1024 threads, 2 elems each
    if (t < 4) {
        auto lb = [&](int tgt) {
            int lo = 0, hi = v;
            while (lo < hi) {
                int mid = (lo + hi) >> 1;
                if (mesh_idx[mid] < tgt) lo = mid + 1; else hi = mid;
            }
            return lo;
        };
        nvpm[t] = lb(t + 1) - lb(t);
    }
    __shared__ unsigned buf0[1024], buf1[1024];
    unsigned x0 = (2 * t < B) ? total[2 * t] : 0u;
    unsigned x1 = (2 * t + 1 < B) ? total[2 * t + 1] : 0u;
    unsigned pair = x0 + x1;
    buf0[t] = pair;
    __syncthreads();
    unsigned* src = buf0;
    unsigned* dst = buf1;
    unsigned vv = pair;
    for (int off = 1; off < 1024; off <<= 1) {
        vv = src[t];
        if (t >= off) vv += src[t - off];
        dst[t] = vv;
        __syncthreads();
        unsigned* tmp = src; src = dst; dst = tmp;
    }
    unsigned excl = vv - pair;
    base[2 * t] = excl;
    base[2 * t + 1] = excl + x0;
    if (t == 1023) base[2048] = vv;
}

__global__ void scatter_kernel(const int* __restrict__ rows,
                               const int* __restrict__ cols,
                               const float* __restrict__ vals,
                               const unsigned short* __restrict__ hist,
                               const unsigned* __restrict__ base,
                               uint2* __restrict__ dst,
                               int nnz, int cpb, int B) {
    __shared__ unsigned cur[BMAX];
    int k = blockIdx.x;
    for (int b = threadIdx.x; b < B; b += blockDim.x)
        cur[b] = base[b] + hist[(size_t)b * NB + k];
    __syncthreads();
    int i0 = k * cpb;
    int i1 = min(i0 + cpb, nnz);
    for (int i = i0 + 2 * (int)threadIdx.x; i < i1; i += 2 * blockDim.x) {
        if (i + 1 < i1) {
            int2   r2 = *(const int2*)(rows + i);
            int2   c2 = *(const int2*)(cols + i);
            float2 v2 = *(const float2*)(vals + i);
            unsigned p0 = atomicAdd(&cur[r2.x >> 10], 1u);
            unsigned p1 = atomicAdd(&cur[r2.y >> 10], 1u);
            uint2 e0, e1;
            e0.x = ((unsigned)(r2.x & (BROWS - 1)) << 21) | (unsigned)c2.x;
            e0.y = __float_as_uint(v2.x);
            e1.x = ((unsigned)(r2.y & (BROWS - 1)) << 21) | (unsigned)c2.y;
            e1.y = __float_as_uint(v2.y);
            dst[p0] = e0;
            dst[p1] = e1;
        } else {
            int r = rows[i];
            unsigned p = atomicAdd(&cur[r >> 10], 1u);
            uint2 e;
            e.x = ((unsigned)(r & (BROWS - 1)) << 21) | (unsigned)cols[i];
            e.y = __float_as_uint(vals[i]);
            dst[p] = e;
        }
    }
}

// One block (512 thr) per bucket: LDS accumulate + fused finalize.
__global__ void bucket_kernel(const uint2* __restrict__ entries,
                              const unsigned* __restrict__ base,
                              const float* __restrict__ verts,
                              const float* __restrict__ coefs,
                              const int* __restrict__ mesh_idx,
                              const int* __restrict__ nvpm,
                              double* __restrict__ partial, int V) {
    __shared__ float ax[BROWS], ay[BROWS], az[BROWS], aw[BROWS];
    int b = blockIdx.x;
    for (int j = threadIdx.x; j < BROWS; j += blockDim.x) {
        ax[j] = 0.f; ay[j] = 0.f; az[j] = 0.f; aw[j] = 0.f;
    }
    __syncthreads();
    unsigned s0 = base[b], s1 = base[b + 1];

    auto accum = [&](unsigned ex, unsigned ey) {
        unsigned lr = ex >> 21;
        unsigned c = ex & 0x1FFFFFu;
        float v = __uint_as_float(ey);
        float x = verts[3 * c + 0];
        float y = verts[3 * c + 1];
        float z = verts[3 * c + 2];
        atomicAdd(&ax[lr], v * x);
        atomicAdd(&ay[lr], v * y);
        atomicAdd(&az[lr], v * z);
        atomicAdd(&aw[lr], v);
    };

    unsigned sA = s0 + (s0 & 1u);
    if (threadIdx.x == 0 && (s0 & 1u) && s0 < s1) {
        uint2 e = entries[s0];
        accum(e.x, e.y);
    }
    for (unsigned i = sA + 2 * threadIdx.x; i + 1 < s1; i += 2 * blockDim.x) {
        uint4 e = *(const uint4*)(entries + i);
        accum(e.x, e.y);
        accum(e.z, e.w);
    }
    if (threadIdx.x == 1 && s1 > sA && ((s1 - sA) & 1u)) {
        uint2 e = entries[s1 - 1];
        accum(e.x, e.y);
    }
    __syncthreads();

    float inv0 = 1.0f / (float)nvpm[0];
    float inv1 = 1.0f / (float)nvpm[1];
    float inv2 = 1.0f / (float)nvpm[2];
    float inv3 = 1.0f / (float)nvpm[3];

    double acc = 0.0;
    int r0 = b << 10;
    for (int j = threadIdx.x; j < BROWS; j += blockDim.x) {
        int r = r0 + j;
        if (r < V) {
            float rs = aw[j];
            float nw = (rs > 0.0f) ? (1.0f / rs) : rs;
            float d0 = ax[j] * nw - verts[3 * r + 0];
            float d1 = ay[j] * nw - verts[3 * r + 1];
            float d2 = az[j] * nw - verts[3 * r + 2];
            float loss = sqrtf(d0 * d0 + d1 * d1 + d2 * d2);
            int m = mesh_idx[r];
            float w = (m == 0) ? inv0 : (m == 1) ? inv1 : (m == 2) ? inv2 : inv3;
            acc += (double)(loss * w * coefs[r]);
        }
    }

    __shared__ double sred[512];
    sred[threadIdx.x] = acc;
    __syncthreads();
    for (int s = blockDim.x / 2; s > 0; s >>= 1) {
        if (threadIdx.x < s) sred[threadIdx.x] += sred[threadIdx.x + s];
        __syncthreads();
    }
    if (threadIdx.x == 0) atomicAdd(partial, sred[0]);
}

__global__ void write_out_kernel(const double* __restrict__ partial,
                                 float* __restrict__ out) {
    if (threadIdx.x == 0 && blockIdx.x == 0)
        out[0] = (float)(partial[0] * 0.25);  // / N_MESHES
}

// ---- Fallback path (R1): global-atomic scatter, needs only 64 + 16V ws ----

__global__ void fb_mesh_counts_kernel(const int* __restrict__ mesh_idx, int v,
                                      int* __restrict__ nvpm) {
    int m = threadIdx.x;
    if (m >= 4) return;
    auto lb = [&](int t) {
        int lo = 0, hi = v;
        while (lo < hi) {
            int mid = (lo + hi) >> 1;
            if (mesh_idx[mid] < t) lo = mid + 1; else hi = mid;
        }
        return lo;
    };
    nvpm[m] = lb(m + 1) - lb(m);
}

__global__ void fb_scatter_kernel(const float* __restrict__ verts,
                                  const float* __restrict__ vals,
                                  const int* __restrict__ rows,
                                  const int* __restrict__ cols,
                                  float* __restrict__ acc, int nnz) {
    int i = blockIdx.x * blockDim.x + threadIdx.x;
    if (i >= nnz) return;
    int r = rows[i];
    int c = cols[i];
    float v = vals[i];
    float* p = acc + 4ll * r;
    atomicAdd(p + 0, v * verts[3 * c + 0]);
    atomicAdd(p + 1, v * verts[3 * c + 1]);
    atomicAdd(p + 2, v * verts[3 * c + 2]);
    atomicAdd(p + 3, v);
}

__global__ void fb_finalize_kernel(const float* __restrict__ verts,
                                   const float* __restrict__ coefs,
                                   const int* __restrict__ mesh_idx,
                                   const float4* __restrict__ acc,
                                   const int* __restrict__ nvpm,
                                   double* __restrict__ partial, int v) {
    float inv0 = 1.0f / (float)nvpm[0];
    float inv1 = 1.0f / (float)nvpm[1];
    float inv2 = 1.0f / (float)nvpm[2];
    float inv3 = 1.0f / (float)nvpm[3];
    double acc_sum = 0.0;
    for (int i = blockIdx.x * blockDim.x + threadIdx.x; i < v;
         i += gridDim.x * blockDim.x) {
        float4 a = acc[i];
        float rs = a.w;
        float nw = (rs > 0.0f) ? (1.0f / rs) : rs;
        float r0 = a.x * nw - verts[3 * i + 0];
        float r1 = a.y * nw - verts[3 * i + 1];
        float r2 = a.z * nw - verts[3 * i + 2];
        float loss = sqrtf(r0 * r0 + r1 * r1 + r2 * r2);
        int m = mesh_idx[i];
        float w = (m == 0) ? inv0 : (m == 1) ? inv1 : (m == 2) ? inv2 : inv3;
        acc_sum += (double)(loss * w * coefs[i]);
    }
    __shared__ double sred[256];
    sred[threadIdx.x] = acc_sum;
    __syncthreads();
    for (int s = blockDim.x / 2; s > 0; s >>= 1) {
        if (threadIdx.x < s) sred[threadIdx.x] += sred[threadIdx.x + s];
        __syncthreads();
    }
    if (threadIdx.x == 0) atomicAdd(partial, sred[0]);
}

extern "C" void kernel_launch(void* const* d_in, const int* in_sizes, int n_in,
                              void* d_out, int out_size, void* d_ws, size_t ws_size,
                              hipStream_t stream) {
    const float* verts    = (const float*)d_in[0];
    const float* lap_vals = (const float*)d_in[1];
    const int*   lap_rows = (const int*)d_in[2];
    const int*   lap_cols = (const int*)d_in[3];
    const int*   mesh_idx = (const int*)d_in[4];
    const float* coefs    = (const float*)d_in[5];
    float* out = (float*)d_out;

    const int V   = in_sizes[0] / 3;
    const int NNZ = in_sizes[1];
    const int B   = (V + BROWS - 1) / BROWS;           // <= BMAX for V <= 2M
    int cpb = (NNZ + NB - 1) / NB;
    cpb = (cpb + 3) & ~3;                              // mult of 4 for int4/int2

    char* ws = (char*)d_ws;
    double*         partial = (double*)(ws + 0);
    int*            nvpm    = (int*)(ws + 8);
    unsigned*       base    = (unsigned*)(ws + 64);
    unsigned*       total   = (unsigned*)(ws + 16384);
    unsigned short* hist    = (unsigned short*)(ws + 32768);
    uint2*          entries = (uint2*)(ws + 32768 + (size_t)BMAX * NB * 2);

    size_t sort_need = 32768 + (size_t)BMAX * NB * 2 + (size_t)NNZ * 8 + 64;

    (void)hipMemsetAsync(d_ws, 0, 64, stream);

    if (ws_size >= sort_need && B <= BMAX) {
        hist_kernel<<<NB, 256, 0, stream>>>(lap_rows, NNZ, cpb, B, hist);
        scan_blocks_kernel<<<B, 256, 0, stream>>>(hist, total);
        scan_buckets_kernel<<<1, 1024, 0, stream>>>(total, base, B,
                                                    mesh_idx, V, nvpm);
        scatter_kernel<<<NB, 256, 0, stream>>>(lap_rows, lap_cols, lap_vals,
                                               hist, base, entries, NNZ, cpb, B);
        bucket_kernel<<<B, 512, 0, stream>>>(entries, base, verts, coefs,
                                             mesh_idx, nvpm, partial, V);
    } else {
        float* acc = (float*)(ws + 64);
        (void)hipMemsetAsync(ws + 64, 0, (size_t)16 * V, stream);
        fb_mesh_counts_kernel<<<1, 64, 0, stream>>>(mesh_idx, V, nvpm);
        fb_scatter_kernel<<<(NNZ + 255) / 256, 256, 0, stream>>>(
            verts, lap_vals, lap_rows, lap_cols, acc, NNZ);
        fb_finalize_kernel<<<2048, 256, 0, stream>>>(
            verts, coefs, mesh_idx, (const float4*)acc, nvpm, partial, V);
    }

    write_out_kernel<<<1, 64, 0, stream>>>(partial, out);
}